// Round 1
// baseline (542.845 us; speedup 1.0000x reference)
//
#include <hip/hip_runtime.h>
#include <hip/hip_bf16.h>
#include <cstdint>

// ---------------- prep kernels ----------------

__global__ void k_init_cnt(int* __restrict__ cnt, int n) {
    int i = blockIdx.x * blockDim.x + threadIdx.x;
    if (i < n) cnt[i] = 0;
}

__global__ void k_count(const int* __restrict__ dstv, int* __restrict__ cnt, int e) {
    int i = blockIdx.x * blockDim.x + threadIdx.x;
    if (i < e) atomicAdd(&cnt[dstv[i]], 1);
}

__global__ void k_dis(const int* __restrict__ cnt, float* __restrict__ dis, int n) {
    int i = blockIdx.x * blockDim.x + threadIdx.x;
    if (i < n) dis[i] = rsqrtf((float)(cnt[i] + 1));   // +1 = self-loop
}

// single-block exclusive scan of cnt -> row_ptr (and fill = row_ptr copy)
__global__ __launch_bounds__(1024) void k_scan(const int* __restrict__ cnt,
                                               int* __restrict__ rp,
                                               int* __restrict__ fill,
                                               int n, int etot) {
    __shared__ int sums[1024];
    int t = threadIdx.x;
    const int SEG = (n + 1023) / 1024;
    int b = t * SEG, en = min(b + SEG, n);
    int s = 0;
    for (int i = b; i < en; ++i) s += cnt[i];
    sums[t] = s;
    __syncthreads();
    for (int off = 1; off < 1024; off <<= 1) {
        int add = (t >= off) ? sums[t - off] : 0;
        __syncthreads();
        sums[t] += add;
        __syncthreads();
    }
    int run = (t == 0) ? 0 : sums[t - 1];
    for (int i = b; i < en; ++i) {
        rp[i] = run; fill[i] = run; run += cnt[i];
    }
    if (t == 0) rp[n] = etot;
}

__global__ void k_fill(const int* __restrict__ srcv, const int* __restrict__ dstv,
                       int* __restrict__ fill, int* __restrict__ col, int e) {
    int i = blockIdx.x * blockDim.x + threadIdx.x;
    if (i < e) {
        int d = dstv[i];
        int pos = atomicAdd(&fill[d], 1);
        col[pos] = srcv[i];
    }
}

// ---------------- GEMM: Y[r][c] = dis[r] * sum_k X[r][k] * W[k][c] ----------------
// K = 128 fixed. 32 rows/block, 4x4 per-thread register tile.

template <int FOUT>
__global__ __launch_bounds__(FOUT * 2) void k_gemm_scale(
        const float* __restrict__ X, const float* __restrict__ W,
        const float* __restrict__ dis, float* __restrict__ Y, int n) {
    constexpr int CT = FOUT / 4;     // col-thread groups (32 or 16)
    constexpr int NT = CT * 8;       // 256 or 128 threads
    __shared__ float xs[32][132];    // 32 rows x 32 k-chunk, padded
    __shared__ float ws[32 * FOUT];  // k-chunk x FOUT
    int tid = threadIdx.x;
    int ct = tid % CT, rt = tid / CT;      // rt in 0..7
    int row0 = blockIdx.x * 32;
    float acc[4][4] = {};

    for (int kt = 0; kt < 4; ++kt) {
        // stage x tile (32 rows x 32 ks), float4 along k
        for (int e = tid; e < 256; e += NT) {
            int r = e >> 3, kq = (e & 7) << 2;
            int row = min(row0 + r, n - 1);
            float4 v = *(const float4*)(X + (size_t)row * 128 + kt * 32 + kq);
            *(float4*)&xs[r][kq] = v;
        }
        // stage W chunk (rows kt*32..+32, contiguous)
        for (int e = tid; e < 32 * FOUT / 4; e += NT) {
            *(float4*)&ws[e * 4] = *(const float4*)&W[kt * 32 * FOUT + e * 4];
        }
        __syncthreads();
#pragma unroll 8
        for (int k = 0; k < 32; ++k) {
            float4 bv = *(const float4*)&ws[k * FOUT + ct * 4];
            float a0 = xs[rt * 4 + 0][k];
            float a1 = xs[rt * 4 + 1][k];
            float a2 = xs[rt * 4 + 2][k];
            float a3 = xs[rt * 4 + 3][k];
            acc[0][0] += a0 * bv.x; acc[0][1] += a0 * bv.y; acc[0][2] += a0 * bv.z; acc[0][3] += a0 * bv.w;
            acc[1][0] += a1 * bv.x; acc[1][1] += a1 * bv.y; acc[1][2] += a1 * bv.z; acc[1][3] += a1 * bv.w;
            acc[2][0] += a2 * bv.x; acc[2][1] += a2 * bv.y; acc[2][2] += a2 * bv.z; acc[2][3] += a2 * bv.w;
            acc[3][0] += a3 * bv.x; acc[3][1] += a3 * bv.y; acc[3][2] += a3 * bv.z; acc[3][3] += a3 * bv.w;
        }
        __syncthreads();
    }
    for (int i = 0; i < 4; ++i) {
        int row = row0 + rt * 4 + i;
        if (row < n) {
            float d = dis[row];
            float4 o = make_float4(acc[i][0] * d, acc[i][1] * d, acc[i][2] * d, acc[i][3] * d);
            *(float4*)&Y[(size_t)row * FOUT + ct * 4] = o;
        }
    }
}

// ---------------- aggregation ----------------
// agg[v] = relu( dis[v] * (hs[v] + sum_{u in nbr(v)} hs[u]) + b )
// one wave per node, 4 nodes per 256-thread block; F=128 as float2 per lane

__global__ __launch_bounds__(256) void k_agg_relu128(
        const float* __restrict__ hs, const int* __restrict__ rp,
        const int* __restrict__ col, const float* __restrict__ dis,
        const float* __restrict__ bias, float* __restrict__ out, int n) {
    int wid = threadIdx.x >> 6;
    int lane = threadIdx.x & 63;
    int v = blockIdx.x * 4 + wid;
    if (v >= n) return;
    const float2* h2 = (const float2*)hs;
    float2 acc = h2[(size_t)v * 64 + lane];   // self-loop term
    int s = rp[v], e = rp[v + 1];
    for (int k = s; k < e; ++k) {
        int u = col[k];
        float2 m = h2[(size_t)u * 64 + lane];
        acc.x += m.x; acc.y += m.y;
    }
    float d = dis[v];
    float2 b = ((const float2*)bias)[lane];
    float ox = fmaxf(d * acc.x + b.x, 0.f);
    float oy = fmaxf(d * acc.y + b.y, 0.f);
    ((float2*)out)[(size_t)v * 64 + lane] = make_float2(ox, oy);
}

// final layer: F=64, one lane per feature, fused bias + log_softmax
__global__ __launch_bounds__(256) void k_agg_lsm64(
        const float* __restrict__ hs, const int* __restrict__ rp,
        const int* __restrict__ col, const float* __restrict__ dis,
        const float* __restrict__ bias, float* __restrict__ out, int n) {
    int wid = threadIdx.x >> 6;
    int lane = threadIdx.x & 63;
    int v = blockIdx.x * 4 + wid;
    if (v >= n) return;
    float acc = hs[(size_t)v * 64 + lane];
    int s = rp[v], e = rp[v + 1];
    for (int k = s; k < e; ++k) acc += hs[(size_t)col[k] * 64 + lane];
    float val = dis[v] * acc + bias[lane];
    float m = val;
    for (int off = 32; off; off >>= 1) m = fmaxf(m, __shfl_xor(m, off, 64));
    float ex = expf(val - m);
    float ss = ex;
    for (int off = 32; off; off >>= 1) ss += __shfl_xor(ss, off, 64);
    out[(size_t)v * 64 + lane] = val - m - logf(ss);
}

// ---------------- launch ----------------

extern "C" void kernel_launch(void* const* d_in, const int* in_sizes, int n_in,
                              void* d_out, int out_size, void* d_ws, size_t ws_size,
                              hipStream_t stream) {
    const float* x  = (const float*)d_in[0];
    const float* W1 = (const float*)d_in[1];
    const float* b1 = (const float*)d_in[2];
    const float* W2 = (const float*)d_in[3];
    const float* b2 = (const float*)d_in[4];
    const float* W3 = (const float*)d_in[5];
    const float* b3 = (const float*)d_in[6];
    const int*   ei = (const int*)d_in[7];

    const int N = in_sizes[0] / 128;
    const int E = in_sizes[7] / 2;
    const int* srcv = ei;
    const int* dstv = ei + E;

    char* ws = (char*)d_ws;
    size_t off = 0;
    auto alloc = [&](size_t bytes) -> void* {
        void* p = ws + off;
        off += (bytes + 255) & ~(size_t)255;
        return p;
    };
    float* dis  = (float*)alloc((size_t)N * 4);
    int*   cnt  = (int*)alloc((size_t)N * 4);
    int*   rp   = (int*)alloc((size_t)(N + 1) * 4);
    int*   fill = (int*)alloc((size_t)N * 4);
    int*   col  = (int*)alloc((size_t)E * 4);
    float* bufA = (float*)alloc((size_t)N * 128 * 4);
    float* bufB = (float*)alloc((size_t)N * 128 * 4);
    float* outp = (float*)d_out;

    const int tb = 256;
    k_init_cnt<<<(N + tb - 1) / tb, tb, 0, stream>>>(cnt, N);
    k_count<<<(E + tb - 1) / tb, tb, 0, stream>>>(dstv, cnt, E);
    k_dis<<<(N + tb - 1) / tb, tb, 0, stream>>>(cnt, dis, N);
    k_scan<<<1, 1024, 0, stream>>>(cnt, rp, fill, N, E);
    k_fill<<<(E + tb - 1) / tb, tb, 0, stream>>>(srcv, dstv, fill, col, E);

    int gblk = (N + 31) / 32;
    int ablk = (N + 3) / 4;
    // layer 1: x -> bufA (hs1) -> bufB (x1)
    k_gemm_scale<128><<<gblk, 256, 0, stream>>>(x, W1, dis, bufA, N);
    k_agg_relu128<<<ablk, 256, 0, stream>>>(bufA, rp, col, dis, b1, bufB, N);
    // layer 2: bufB -> bufA (hs2) -> bufB (x2)
    k_gemm_scale<128><<<gblk, 256, 0, stream>>>(bufB, W2, dis, bufA, N);
    k_agg_relu128<<<ablk, 256, 0, stream>>>(bufA, rp, col, dis, b2, bufB, N);
    // layer 3: bufB -> bufA (hs3, F=64) -> d_out (log_softmax)
    k_gemm_scale<64><<<gblk, 128, 0, stream>>>(bufB, W3, dis, bufA, N);
    k_agg_lsm64<<<ablk, 256, 0, stream>>>(bufA, rp, col, dis, b3, outp, N);
}

// Round 2
// 441.339 us; speedup vs baseline: 1.2300x; 1.2300x over previous
//
#include <hip/hip_runtime.h>
#include <hip/hip_bf16.h>
#include <cstdint>

// ---------------- prep kernels ----------------

__global__ void k_init_cnt(int* __restrict__ cnt, int n) {
    int i = blockIdx.x * blockDim.x + threadIdx.x;
    if (i < n) cnt[i] = 0;
}

__global__ void k_count(const int* __restrict__ dstv, int* __restrict__ cnt, int e) {
    int i = blockIdx.x * blockDim.x + threadIdx.x;
    if (i < e) atomicAdd(&cnt[dstv[i]], 1);
}

__global__ void k_dis(const int* __restrict__ cnt, float* __restrict__ dis, int n) {
    int i = blockIdx.x * blockDim.x + threadIdx.x;
    if (i < n) dis[i] = rsqrtf((float)(cnt[i] + 1));   // +1 = self-loop
}

// ---------- two-level scan: cnt -> rp (exclusive), fill = rp copy ----------
// level 1: per-block (1024 items) sums

__global__ __launch_bounds__(256) void k_partial_sums(const int* __restrict__ cnt,
                                                      int* __restrict__ partial, int n) {
    int base = blockIdx.x * 1024 + threadIdx.x * 4;
    int4 v = make_int4(0, 0, 0, 0);
    if (base + 3 < n) v = *(const int4*)(cnt + base);
    else {
        if (base + 0 < n) v.x = cnt[base + 0];
        if (base + 1 < n) v.y = cnt[base + 1];
        if (base + 2 < n) v.z = cnt[base + 2];
    }
    int s = v.x + v.y + v.z + v.w;
    for (int off = 32; off; off >>= 1) s += __shfl_xor(s, off, 64);
    __shared__ int wsum[4];
    int lane = threadIdx.x & 63, wid = threadIdx.x >> 6;
    if (lane == 0) wsum[wid] = s;
    __syncthreads();
    if (threadIdx.x == 0) partial[blockIdx.x] = wsum[0] + wsum[1] + wsum[2] + wsum[3];
}

// level 2: single-block exclusive scan of block sums (nb <= 1024)
__global__ __launch_bounds__(1024) void k_scan_partials(int* __restrict__ partial, int nb,
                                                        int* __restrict__ rp, int n, int etot) {
    __shared__ int s[1024];
    int t = threadIdx.x;
    int v = (t < nb) ? partial[t] : 0;
    s[t] = v;
    __syncthreads();
    for (int off = 1; off < 1024; off <<= 1) {
        int add = (t >= off) ? s[t - off] : 0;
        __syncthreads();
        s[t] += add;
        __syncthreads();
    }
    if (t < nb) partial[t] = s[t] - v;   // exclusive block offset
    if (t == 0) rp[n] = etot;
}

// level 3: per-block local scan + block offset -> rp, fill
__global__ __launch_bounds__(256) void k_local_scan(const int* __restrict__ cnt,
                                                    const int* __restrict__ partial,
                                                    int* __restrict__ rp,
                                                    int* __restrict__ fill, int n) {
    int base = blockIdx.x * 1024 + threadIdx.x * 4;
    int4 v = make_int4(0, 0, 0, 0);
    if (base + 3 < n) v = *(const int4*)(cnt + base);
    else {
        if (base + 0 < n) v.x = cnt[base + 0];
        if (base + 1 < n) v.y = cnt[base + 1];
        if (base + 2 < n) v.z = cnt[base + 2];
    }
    int tsum = v.x + v.y + v.z + v.w;
    int lane = threadIdx.x & 63, wid = threadIdx.x >> 6;
    int inc = tsum;
    for (int off = 1; off < 64; off <<= 1) {
        int y = __shfl_up(inc, off, 64);
        if (lane >= off) inc += y;
    }
    int exc = inc - tsum;
    __shared__ int wtot[4];
    if (lane == 63) wtot[wid] = inc;
    __syncthreads();
    int woff = 0;
    for (int w = 0; w < wid; ++w) woff += wtot[w];
    int p0 = partial[blockIdx.x] + woff + exc;
    int p1 = p0 + v.x, p2 = p1 + v.y, p3 = p2 + v.z;
    if (base + 3 < n) {
        *(int4*)&rp[base]   = make_int4(p0, p1, p2, p3);
        *(int4*)&fill[base] = make_int4(p0, p1, p2, p3);
    } else {
        if (base + 0 < n) { rp[base + 0] = p0; fill[base + 0] = p0; }
        if (base + 1 < n) { rp[base + 1] = p1; fill[base + 1] = p1; }
        if (base + 2 < n) { rp[base + 2] = p2; fill[base + 2] = p2; }
    }
}

__global__ void k_fill(const int* __restrict__ srcv, const int* __restrict__ dstv,
                       int* __restrict__ fill, int* __restrict__ col, int e) {
    int i = blockIdx.x * blockDim.x + threadIdx.x;
    if (i < e) {
        int d = dstv[i];
        int pos = atomicAdd(&fill[d], 1);
        col[pos] = srcv[i];
    }
}

// ---------------- GEMM: Y[r][c] = dis[r] * sum_k X[r][k] * W[k][c] ----------------
// K = 128 fixed. 32 rows/block, 4x4 per-thread register tile.

template <int FOUT>
__global__ __launch_bounds__(FOUT * 2) void k_gemm_scale(
        const float* __restrict__ X, const float* __restrict__ W,
        const float* __restrict__ dis, float* __restrict__ Y, int n) {
    constexpr int CT = FOUT / 4;     // col-thread groups (32 or 16)
    constexpr int NT = CT * 8;       // 256 or 128 threads
    __shared__ float xs[32][132];    // 32 rows x 32 k-chunk, padded
    __shared__ float ws[32 * FOUT];  // k-chunk x FOUT
    int tid = threadIdx.x;
    int ct = tid % CT, rt = tid / CT;      // rt in 0..7
    int row0 = blockIdx.x * 32;
    float acc[4][4] = {};

    for (int kt = 0; kt < 4; ++kt) {
        for (int e = tid; e < 256; e += NT) {
            int r = e >> 3, kq = (e & 7) << 2;
            int row = min(row0 + r, n - 1);
            float4 v = *(const float4*)(X + (size_t)row * 128 + kt * 32 + kq);
            *(float4*)&xs[r][kq] = v;
        }
        for (int e = tid; e < 32 * FOUT / 4; e += NT) {
            *(float4*)&ws[e * 4] = *(const float4*)&W[kt * 32 * FOUT + e * 4];
        }
        __syncthreads();
#pragma unroll 8
        for (int k = 0; k < 32; ++k) {
            float4 bv = *(const float4*)&ws[k * FOUT + ct * 4];
            float a0 = xs[rt * 4 + 0][k];
            float a1 = xs[rt * 4 + 1][k];
            float a2 = xs[rt * 4 + 2][k];
            float a3 = xs[rt * 4 + 3][k];
            acc[0][0] += a0 * bv.x; acc[0][1] += a0 * bv.y; acc[0][2] += a0 * bv.z; acc[0][3] += a0 * bv.w;
            acc[1][0] += a1 * bv.x; acc[1][1] += a1 * bv.y; acc[1][2] += a1 * bv.z; acc[1][3] += a1 * bv.w;
            acc[2][0] += a2 * bv.x; acc[2][1] += a2 * bv.y; acc[2][2] += a2 * bv.z; acc[2][3] += a2 * bv.w;
            acc[3][0] += a3 * bv.x; acc[3][1] += a3 * bv.y; acc[3][2] += a3 * bv.z; acc[3][3] += a3 * bv.w;
        }
        __syncthreads();
    }
    for (int i = 0; i < 4; ++i) {
        int row = row0 + rt * 4 + i;
        if (row < n) {
            float d = dis[row];
            float4 o = make_float4(acc[i][0] * d, acc[i][1] * d, acc[i][2] * d, acc[i][3] * d);
            *(float4*)&Y[(size_t)row * FOUT + ct * 4] = o;
        }
    }
}

// ---------------- aggregation ----------------

__global__ __launch_bounds__(256) void k_agg_relu128(
        const float* __restrict__ hs, const int* __restrict__ rp,
        const int* __restrict__ col, const float* __restrict__ dis,
        const float* __restrict__ bias, float* __restrict__ out, int n) {
    int wid = threadIdx.x >> 6;
    int lane = threadIdx.x & 63;
    int v = blockIdx.x * 4 + wid;
    if (v >= n) return;
    const float2* h2 = (const float2*)hs;
    float2 acc = h2[(size_t)v * 64 + lane];   // self-loop term
    int s = rp[v], e = rp[v + 1];
    for (int k = s; k < e; ++k) {
        int u = col[k];
        float2 m = h2[(size_t)u * 64 + lane];
        acc.x += m.x; acc.y += m.y;
    }
    float d = dis[v];
    float2 b = ((const float2*)bias)[lane];
    float ox = fmaxf(d * acc.x + b.x, 0.f);
    float oy = fmaxf(d * acc.y + b.y, 0.f);
    ((float2*)out)[(size_t)v * 64 + lane] = make_float2(ox, oy);
}

__global__ __launch_bounds__(256) void k_agg_lsm64(
        const float* __restrict__ hs, const int* __restrict__ rp,
        const int* __restrict__ col, const float* __restrict__ dis,
        const float* __restrict__ bias, float* __restrict__ out, int n) {
    int wid = threadIdx.x >> 6;
    int lane = threadIdx.x & 63;
    int v = blockIdx.x * 4 + wid;
    if (v >= n) return;
    float acc = hs[(size_t)v * 64 + lane];
    int s = rp[v], e = rp[v + 1];
    for (int k = s; k < e; ++k) acc += hs[(size_t)col[k] * 64 + lane];
    float val = dis[v] * acc + bias[lane];
    float m = val;
    for (int off = 32; off; off >>= 1) m = fmaxf(m, __shfl_xor(m, off, 64));
    float ex = expf(val - m);
    float ss = ex;
    for (int off = 32; off; off >>= 1) ss += __shfl_xor(ss, off, 64);
    out[(size_t)v * 64 + lane] = val - m - logf(ss);
}

// ---------------- launch ----------------

extern "C" void kernel_launch(void* const* d_in, const int* in_sizes, int n_in,
                              void* d_out, int out_size, void* d_ws, size_t ws_size,
                              hipStream_t stream) {
    const float* x  = (const float*)d_in[0];
    const float* W1 = (const float*)d_in[1];
    const float* b1 = (const float*)d_in[2];
    const float* W2 = (const float*)d_in[3];
    const float* b2 = (const float*)d_in[4];
    const float* W3 = (const float*)d_in[5];
    const float* b3 = (const float*)d_in[6];
    const int*   ei = (const int*)d_in[7];

    const int N = in_sizes[0] / 128;
    const int E = in_sizes[7] / 2;
    const int* srcv = ei;
    const int* dstv = ei + E;

    char* ws = (char*)d_ws;
    size_t off = 0;
    auto alloc = [&](size_t bytes) -> void* {
        void* p = ws + off;
        off += (bytes + 255) & ~(size_t)255;
        return p;
    };
    float* dis  = (float*)alloc((size_t)N * 4);
    int*   cnt  = (int*)alloc((size_t)N * 4);
    int*   rp   = (int*)alloc((size_t)(N + 1) * 4);
    int*   fill = (int*)alloc((size_t)N * 4);
    int*   col  = (int*)alloc((size_t)E * 4);
    int*   part = (int*)alloc((size_t)1024 * 4);
    float* bufA = (float*)alloc((size_t)N * 128 * 4);
    float* bufB = (float*)alloc((size_t)N * 128 * 4);
    float* outp = (float*)d_out;

    const int tb = 256;
    const int nb = (N + 1023) / 1024;
    k_init_cnt<<<(N + tb - 1) / tb, tb, 0, stream>>>(cnt, N);
    k_count<<<(E + tb - 1) / tb, tb, 0, stream>>>(dstv, cnt, E);
    k_dis<<<(N + tb - 1) / tb, tb, 0, stream>>>(cnt, dis, N);
    k_partial_sums<<<nb, 256, 0, stream>>>(cnt, part, N);
    k_scan_partials<<<1, 1024, 0, stream>>>(part, nb, rp, N, E);
    k_local_scan<<<nb, 256, 0, stream>>>(cnt, part, rp, fill, N);
    k_fill<<<(E + tb - 1) / tb, tb, 0, stream>>>(srcv, dstv, fill, col, E);

    int gblk = (N + 31) / 32;
    int ablk = (N + 3) / 4;
    k_gemm_scale<128><<<gblk, 256, 0, stream>>>(x, W1, dis, bufA, N);
    k_agg_relu128<<<ablk, 256, 0, stream>>>(bufA, rp, col, dis, b1, bufB, N);
    k_gemm_scale<128><<<gblk, 256, 0, stream>>>(bufB, W2, dis, bufA, N);
    k_agg_relu128<<<ablk, 256, 0, stream>>>(bufA, rp, col, dis, b2, bufB, N);
    k_gemm_scale<64><<<gblk, 128, 0, stream>>>(bufB, W3, dis, bufA, N);
    k_agg_lsm64<<<ablk, 256, 0, stream>>>(bufA, rp, col, dis, b3, outp, N);
}

// Round 3
// 332.976 us; speedup vs baseline: 1.6303x; 1.3254x over previous
//
#include <hip/hip_runtime.h>
#include <hip/hip_bf16.h>
#include <cstdint>

// ---------------- prep kernels ----------------

__global__ void k_init_cnt(int* __restrict__ cnt, int n) {
    int i = blockIdx.x * blockDim.x + threadIdx.x;
    if (i < n) cnt[i] = 0;
}

__global__ void k_count(const int* __restrict__ dstv, int* __restrict__ cnt, int e) {
    int i = blockIdx.x * blockDim.x + threadIdx.x;
    if (i < e) atomicAdd(&cnt[dstv[i]], 1);
}

__global__ void k_dis(const int* __restrict__ cnt, float* __restrict__ dis, int n) {
    int i = blockIdx.x * blockDim.x + threadIdx.x;
    if (i < n) dis[i] = rsqrtf((float)(cnt[i] + 1));   // +1 = self-loop
}

// ---------- two-level scan: cnt -> rp (exclusive), fill = rp copy ----------

__global__ __launch_bounds__(256) void k_partial_sums(const int* __restrict__ cnt,
                                                      int* __restrict__ partial, int n) {
    int base = blockIdx.x * 1024 + threadIdx.x * 4;
    int4 v = make_int4(0, 0, 0, 0);
    if (base + 3 < n) v = *(const int4*)(cnt + base);
    else {
        if (base + 0 < n) v.x = cnt[base + 0];
        if (base + 1 < n) v.y = cnt[base + 1];
        if (base + 2 < n) v.z = cnt[base + 2];
    }
    int s = v.x + v.y + v.z + v.w;
    for (int off = 32; off; off >>= 1) s += __shfl_xor(s, off, 64);
    __shared__ int wsum[4];
    int lane = threadIdx.x & 63, wid = threadIdx.x >> 6;
    if (lane == 0) wsum[wid] = s;
    __syncthreads();
    if (threadIdx.x == 0) partial[blockIdx.x] = wsum[0] + wsum[1] + wsum[2] + wsum[3];
}

__global__ __launch_bounds__(1024) void k_scan_partials(int* __restrict__ partial, int nb,
                                                        int* __restrict__ rp, int n, int etot) {
    __shared__ int s[1024];
    int t = threadIdx.x;
    int v = (t < nb) ? partial[t] : 0;
    s[t] = v;
    __syncthreads();
    for (int off = 1; off < 1024; off <<= 1) {
        int add = (t >= off) ? s[t - off] : 0;
        __syncthreads();
        s[t] += add;
        __syncthreads();
    }
    if (t < nb) partial[t] = s[t] - v;
    if (t == 0) rp[n] = etot;
}

__global__ __launch_bounds__(256) void k_local_scan(const int* __restrict__ cnt,
                                                    const int* __restrict__ partial,
                                                    int* __restrict__ rp,
                                                    int* __restrict__ fill, int n) {
    int base = blockIdx.x * 1024 + threadIdx.x * 4;
    int4 v = make_int4(0, 0, 0, 0);
    if (base + 3 < n) v = *(const int4*)(cnt + base);
    else {
        if (base + 0 < n) v.x = cnt[base + 0];
        if (base + 1 < n) v.y = cnt[base + 1];
        if (base + 2 < n) v.z = cnt[base + 2];
    }
    int tsum = v.x + v.y + v.z + v.w;
    int lane = threadIdx.x & 63, wid = threadIdx.x >> 6;
    int inc = tsum;
    for (int off = 1; off < 64; off <<= 1) {
        int y = __shfl_up(inc, off, 64);
        if (lane >= off) inc += y;
    }
    int exc = inc - tsum;
    __shared__ int wtot[4];
    if (lane == 63) wtot[wid] = inc;
    __syncthreads();
    int woff = 0;
    for (int w = 0; w < wid; ++w) woff += wtot[w];
    int p0 = partial[blockIdx.x] + woff + exc;
    int p1 = p0 + v.x, p2 = p1 + v.y, p3 = p2 + v.z;
    if (base + 3 < n) {
        *(int4*)&rp[base]   = make_int4(p0, p1, p2, p3);
        *(int4*)&fill[base] = make_int4(p0, p1, p2, p3);
    } else {
        if (base + 0 < n) { rp[base + 0] = p0; fill[base + 0] = p0; }
        if (base + 1 < n) { rp[base + 1] = p1; fill[base + 1] = p1; }
        if (base + 2 < n) { rp[base + 2] = p2; fill[base + 2] = p2; }
    }
}

__global__ void k_fill(const int* __restrict__ srcv, const int* __restrict__ dstv,
                       int* __restrict__ fill, int* __restrict__ col, int e) {
    int i = blockIdx.x * blockDim.x + threadIdx.x;
    if (i < e) {
        int d = dstv[i];
        int pos = atomicAdd(&fill[d], 1);
        col[pos] = srcv[i];
    }
}

// ---------------- GEMM: Y[r][c] = dis[r] * sum_k X[r][k] * W[k][c] ----------------

template <int FOUT>
__global__ __launch_bounds__(FOUT * 2) void k_gemm_scale(
        const float* __restrict__ X, const float* __restrict__ W,
        const float* __restrict__ dis, float* __restrict__ Y, int n) {
    constexpr int CT = FOUT / 4;
    constexpr int NT = CT * 8;
    __shared__ float xs[32][132];
    __shared__ float ws[32 * FOUT];
    int tid = threadIdx.x;
    int ct = tid % CT, rt = tid / CT;
    int row0 = blockIdx.x * 32;
    float acc[4][4] = {};

    for (int kt = 0; kt < 4; ++kt) {
        for (int e = tid; e < 256; e += NT) {
            int r = e >> 3, kq = (e & 7) << 2;
            int row = min(row0 + r, n - 1);
            float4 v = *(const float4*)(X + (size_t)row * 128 + kt * 32 + kq);
            *(float4*)&xs[r][kq] = v;
        }
        for (int e = tid; e < 32 * FOUT / 4; e += NT) {
            *(float4*)&ws[e * 4] = *(const float4*)&W[kt * 32 * FOUT + e * 4];
        }
        __syncthreads();
#pragma unroll 8
        for (int k = 0; k < 32; ++k) {
            float4 bv = *(const float4*)&ws[k * FOUT + ct * 4];
            float a0 = xs[rt * 4 + 0][k];
            float a1 = xs[rt * 4 + 1][k];
            float a2 = xs[rt * 4 + 2][k];
            float a3 = xs[rt * 4 + 3][k];
            acc[0][0] += a0 * bv.x; acc[0][1] += a0 * bv.y; acc[0][2] += a0 * bv.z; acc[0][3] += a0 * bv.w;
            acc[1][0] += a1 * bv.x; acc[1][1] += a1 * bv.y; acc[1][2] += a1 * bv.z; acc[1][3] += a1 * bv.w;
            acc[2][0] += a2 * bv.x; acc[2][1] += a2 * bv.y; acc[2][2] += a2 * bv.z; acc[2][3] += a2 * bv.w;
            acc[3][0] += a3 * bv.x; acc[3][1] += a3 * bv.y; acc[3][2] += a3 * bv.z; acc[3][3] += a3 * bv.w;
        }
        __syncthreads();
    }
    for (int i = 0; i < 4; ++i) {
        int row = row0 + rt * 4 + i;
        if (row < n) {
            float d = dis[row];
            float4 o = make_float4(acc[i][0] * d, acc[i][1] * d, acc[i][2] * d, acc[i][3] * d);
            *(float4*)&Y[(size_t)row * FOUT + ct * 4] = o;
        }
    }
}

// ---------------- aggregation (8-wide edge-batched gathers) ----------------
// agg[v] = relu( dis[v] * (hs[v] + sum_{u in nbr(v)} hs[u]) + b )

__global__ __launch_bounds__(256) void k_agg_relu128(
        const float* __restrict__ hs, const int* __restrict__ rp,
        const int* __restrict__ col, const float* __restrict__ dis,
        const float* __restrict__ bias, float* __restrict__ out, int n) {
    int wid = threadIdx.x >> 6;
    int lane = threadIdx.x & 63;
    int v = blockIdx.x * 4 + wid;
    if (v >= n) return;
    const float2* h2 = (const float2*)hs;
    float2 acc = h2[(size_t)v * 64 + lane];   // self-loop term
    int s = __builtin_amdgcn_readfirstlane(rp[v]);
    int e = __builtin_amdgcn_readfirstlane(rp[v + 1]);
    int k = s;
    for (; k + 8 <= e; k += 8) {
        int u0 = col[k + 0], u1 = col[k + 1], u2 = col[k + 2], u3 = col[k + 3];
        int u4 = col[k + 4], u5 = col[k + 5], u6 = col[k + 6], u7 = col[k + 7];
        float2 m0 = h2[(size_t)u0 * 64 + lane];
        float2 m1 = h2[(size_t)u1 * 64 + lane];
        float2 m2 = h2[(size_t)u2 * 64 + lane];
        float2 m3 = h2[(size_t)u3 * 64 + lane];
        float2 m4 = h2[(size_t)u4 * 64 + lane];
        float2 m5 = h2[(size_t)u5 * 64 + lane];
        float2 m6 = h2[(size_t)u6 * 64 + lane];
        float2 m7 = h2[(size_t)u7 * 64 + lane];
        acc.x += ((m0.x + m1.x) + (m2.x + m3.x)) + ((m4.x + m5.x) + (m6.x + m7.x));
        acc.y += ((m0.y + m1.y) + (m2.y + m3.y)) + ((m4.y + m5.y) + (m6.y + m7.y));
    }
    if (k + 4 <= e) {
        int u0 = col[k + 0], u1 = col[k + 1], u2 = col[k + 2], u3 = col[k + 3];
        float2 m0 = h2[(size_t)u0 * 64 + lane];
        float2 m1 = h2[(size_t)u1 * 64 + lane];
        float2 m2 = h2[(size_t)u2 * 64 + lane];
        float2 m3 = h2[(size_t)u3 * 64 + lane];
        acc.x += (m0.x + m1.x) + (m2.x + m3.x);
        acc.y += (m0.y + m1.y) + (m2.y + m3.y);
        k += 4;
    }
    for (; k < e; ++k) {
        float2 m = h2[(size_t)col[k] * 64 + lane];
        acc.x += m.x; acc.y += m.y;
    }
    float d = dis[v];
    float2 b = ((const float2*)bias)[lane];
    float ox = fmaxf(d * acc.x + b.x, 0.f);
    float oy = fmaxf(d * acc.y + b.y, 0.f);
    ((float2*)out)[(size_t)v * 64 + lane] = make_float2(ox, oy);
}

__global__ __launch_bounds__(256) void k_agg_lsm64(
        const float* __restrict__ hs, const int* __restrict__ rp,
        const int* __restrict__ col, const float* __restrict__ dis,
        const float* __restrict__ bias, float* __restrict__ out, int n) {
    int wid = threadIdx.x >> 6;
    int lane = threadIdx.x & 63;
    int v = blockIdx.x * 4 + wid;
    if (v >= n) return;
    float acc = hs[(size_t)v * 64 + lane];
    int s = __builtin_amdgcn_readfirstlane(rp[v]);
    int e = __builtin_amdgcn_readfirstlane(rp[v + 1]);
    int k = s;
    for (; k + 8 <= e; k += 8) {
        int u0 = col[k + 0], u1 = col[k + 1], u2 = col[k + 2], u3 = col[k + 3];
        int u4 = col[k + 4], u5 = col[k + 5], u6 = col[k + 6], u7 = col[k + 7];
        float m0 = hs[(size_t)u0 * 64 + lane];
        float m1 = hs[(size_t)u1 * 64 + lane];
        float m2 = hs[(size_t)u2 * 64 + lane];
        float m3 = hs[(size_t)u3 * 64 + lane];
        float m4 = hs[(size_t)u4 * 64 + lane];
        float m5 = hs[(size_t)u5 * 64 + lane];
        float m6 = hs[(size_t)u6 * 64 + lane];
        float m7 = hs[(size_t)u7 * 64 + lane];
        acc += ((m0 + m1) + (m2 + m3)) + ((m4 + m5) + (m6 + m7));
    }
    if (k + 4 <= e) {
        float m0 = hs[(size_t)col[k + 0] * 64 + lane];
        float m1 = hs[(size_t)col[k + 1] * 64 + lane];
        float m2 = hs[(size_t)col[k + 2] * 64 + lane];
        float m3 = hs[(size_t)col[k + 3] * 64 + lane];
        acc += (m0 + m1) + (m2 + m3);
        k += 4;
    }
    for (; k < e; ++k) acc += hs[(size_t)col[k] * 64 + lane];
    float val = dis[v] * acc + bias[lane];
    float m = val;
    for (int off = 32; off; off >>= 1) m = fmaxf(m, __shfl_xor(m, off, 64));
    float ex = expf(val - m);
    float ss = ex;
    for (int off = 32; off; off >>= 1) ss += __shfl_xor(ss, off, 64);
    out[(size_t)v * 64 + lane] = val - m - logf(ss);
}

// ---------------- launch ----------------

extern "C" void kernel_launch(void* const* d_in, const int* in_sizes, int n_in,
                              void* d_out, int out_size, void* d_ws, size_t ws_size,
                              hipStream_t stream) {
    const float* x  = (const float*)d_in[0];
    const float* W1 = (const float*)d_in[1];
    const float* b1 = (const float*)d_in[2];
    const float* W2 = (const float*)d_in[3];
    const float* b2 = (const float*)d_in[4];
    const float* W3 = (const float*)d_in[5];
    const float* b3 = (const float*)d_in[6];
    const int*   ei = (const int*)d_in[7];

    const int N = in_sizes[0] / 128;
    const int E = in_sizes[7] / 2;
    const int* srcv = ei;
    const int* dstv = ei + E;

    char* ws = (char*)d_ws;
    size_t off = 0;
    auto alloc = [&](size_t bytes) -> void* {
        void* p = ws + off;
        off += (bytes + 255) & ~(size_t)255;
        return p;
    };
    float* dis  = (float*)alloc((size_t)N * 4);
    int*   cnt  = (int*)alloc((size_t)N * 4);
    int*   rp   = (int*)alloc((size_t)(N + 1) * 4);
    int*   fill = (int*)alloc((size_t)N * 4);
    int*   col  = (int*)alloc((size_t)E * 4);
    int*   part = (int*)alloc((size_t)1024 * 4);
    float* bufA = (float*)alloc((size_t)N * 128 * 4);
    float* bufB = (float*)alloc((size_t)N * 128 * 4);
    float* outp = (float*)d_out;

    const int tb = 256;
    const int nb = (N + 1023) / 1024;
    k_init_cnt<<<(N + tb - 1) / tb, tb, 0, stream>>>(cnt, N);
    k_count<<<(E + tb - 1) / tb, tb, 0, stream>>>(dstv, cnt, E);
    k_dis<<<(N + tb - 1) / tb, tb, 0, stream>>>(cnt, dis, N);
    k_partial_sums<<<nb, 256, 0, stream>>>(cnt, part, N);
    k_scan_partials<<<1, 1024, 0, stream>>>(part, nb, rp, N, E);
    k_local_scan<<<nb, 256, 0, stream>>>(cnt, part, rp, fill, N);
    k_fill<<<(E + tb - 1) / tb, tb, 0, stream>>>(srcv, dstv, fill, col, E);

    int gblk = (N + 31) / 32;
    int ablk = (N + 3) / 4;
    k_gemm_scale<128><<<gblk, 256, 0, stream>>>(x, W1, dis, bufA, N);
    k_agg_relu128<<<ablk, 256, 0, stream>>>(bufA, rp, col, dis, b1, bufB, N);
    k_gemm_scale<128><<<gblk, 256, 0, stream>>>(bufB, W2, dis, bufA, N);
    k_agg_relu128<<<ablk, 256, 0, stream>>>(bufA, rp, col, dis, b2, bufB, N);
    k_gemm_scale<64><<<gblk, 128, 0, stream>>>(bufB, W3, dis, bufA, N);
    k_agg_lsm64<<<ablk, 256, 0, stream>>>(bufA, rp, col, dis, b3, outp, N);
}

// Round 4
// 278.105 us; speedup vs baseline: 1.9519x; 1.1973x over previous
//
#include <hip/hip_runtime.h>
#include <hip/hip_bf16.h>
#include <cstdint>

typedef unsigned int uint32;
typedef unsigned short ushort16;

__device__ inline uint32 pack_bf16(float a, float b) {
    uint32 ua = __float_as_uint(a);
    ua += 0x7fff + ((ua >> 16) & 1);
    uint32 ub = __float_as_uint(b);
    ub += 0x7fff + ((ub >> 16) & 1);
    return (ua >> 16) | (ub & 0xffff0000u);
}
__device__ inline float bf_lo(uint32 w) { return __uint_as_float(w << 16); }
__device__ inline float bf_hi(uint32 w) { return __uint_as_float(w & 0xffff0000u); }

// ---------------- prep kernels ----------------

__global__ void k_init_cnt(int* __restrict__ cnt, int n) {
    int i = blockIdx.x * blockDim.x + threadIdx.x;
    if (i < n) cnt[i] = 0;
}

__global__ void k_count(const int* __restrict__ dstv, int* __restrict__ cnt, int e) {
    int i = blockIdx.x * blockDim.x + threadIdx.x;
    if (i < e) atomicAdd(&cnt[dstv[i]], 1);
}

__global__ void k_dis(const int* __restrict__ cnt, float* __restrict__ dis, int n) {
    int i = blockIdx.x * blockDim.x + threadIdx.x;
    if (i < n) dis[i] = rsqrtf((float)(cnt[i] + 1));   // +1 = self-loop
}

// ---------- two-level scan: cnt -> rp (exclusive), fill = rp copy ----------

__global__ __launch_bounds__(256) void k_partial_sums(const int* __restrict__ cnt,
                                                      int* __restrict__ partial, int n) {
    int base = blockIdx.x * 1024 + threadIdx.x * 4;
    int4 v = make_int4(0, 0, 0, 0);
    if (base + 3 < n) v = *(const int4*)(cnt + base);
    else {
        if (base + 0 < n) v.x = cnt[base + 0];
        if (base + 1 < n) v.y = cnt[base + 1];
        if (base + 2 < n) v.z = cnt[base + 2];
    }
    int s = v.x + v.y + v.z + v.w;
    for (int off = 32; off; off >>= 1) s += __shfl_xor(s, off, 64);
    __shared__ int wsum[4];
    int lane = threadIdx.x & 63, wid = threadIdx.x >> 6;
    if (lane == 0) wsum[wid] = s;
    __syncthreads();
    if (threadIdx.x == 0) partial[blockIdx.x] = wsum[0] + wsum[1] + wsum[2] + wsum[3];
}

__global__ __launch_bounds__(1024) void k_scan_partials(int* __restrict__ partial, int nb,
                                                        int* __restrict__ rp, int n, int etot) {
    __shared__ int s[1024];
    int t = threadIdx.x;
    int v = (t < nb) ? partial[t] : 0;
    s[t] = v;
    __syncthreads();
    for (int off = 1; off < 1024; off <<= 1) {
        int add = (t >= off) ? s[t - off] : 0;
        __syncthreads();
        s[t] += add;
        __syncthreads();
    }
    if (t < nb) partial[t] = s[t] - v;
    if (t == 0) rp[n] = etot;
}

__global__ __launch_bounds__(256) void k_local_scan(const int* __restrict__ cnt,
                                                    const int* __restrict__ partial,
                                                    int* __restrict__ rp,
                                                    int* __restrict__ fill, int n) {
    int base = blockIdx.x * 1024 + threadIdx.x * 4;
    int4 v = make_int4(0, 0, 0, 0);
    if (base + 3 < n) v = *(const int4*)(cnt + base);
    else {
        if (base + 0 < n) v.x = cnt[base + 0];
        if (base + 1 < n) v.y = cnt[base + 1];
        if (base + 2 < n) v.z = cnt[base + 2];
    }
    int tsum = v.x + v.y + v.z + v.w;
    int lane = threadIdx.x & 63, wid = threadIdx.x >> 6;
    int inc = tsum;
    for (int off = 1; off < 64; off <<= 1) {
        int y = __shfl_up(inc, off, 64);
        if (lane >= off) inc += y;
    }
    int exc = inc - tsum;
    __shared__ int wtot[4];
    if (lane == 63) wtot[wid] = inc;
    __syncthreads();
    int woff = 0;
    for (int w = 0; w < wid; ++w) woff += wtot[w];
    int p0 = partial[blockIdx.x] + woff + exc;
    int p1 = p0 + v.x, p2 = p1 + v.y, p3 = p2 + v.z;
    if (base + 3 < n) {
        *(int4*)&rp[base]   = make_int4(p0, p1, p2, p3);
        *(int4*)&fill[base] = make_int4(p0, p1, p2, p3);
    } else {
        if (base + 0 < n) { rp[base + 0] = p0; fill[base + 0] = p0; }
        if (base + 1 < n) { rp[base + 1] = p1; fill[base + 1] = p1; }
        if (base + 2 < n) { rp[base + 2] = p2; fill[base + 2] = p2; }
    }
}

__global__ void k_fill(const int* __restrict__ srcv, const int* __restrict__ dstv,
                       int* __restrict__ fill, int* __restrict__ col, int e) {
    int i = blockIdx.x * blockDim.x + threadIdx.x;
    if (i < e) {
        int d = dstv[i];
        int pos = atomicAdd(&fill[d], 1);
        col[pos] = srcv[i];
    }
}

// ------- GEMM: Yb[r][c] = bf16( dis[r] * sum_k X[r][k] * W[k][c] ) -------

template <int FOUT>
__global__ __launch_bounds__(FOUT * 2) void k_gemm_scale(
        const float* __restrict__ X, const float* __restrict__ W,
        const float* __restrict__ dis, uint32* __restrict__ Yb, int n) {
    constexpr int CT = FOUT / 4;
    constexpr int NT = CT * 8;
    __shared__ float xs[32][132];
    __shared__ float ws[32 * FOUT];
    int tid = threadIdx.x;
    int ct = tid % CT, rt = tid / CT;
    int row0 = blockIdx.x * 32;
    float acc[4][4] = {};

    for (int kt = 0; kt < 4; ++kt) {
        for (int e = tid; e < 256; e += NT) {
            int r = e >> 3, kq = (e & 7) << 2;
            int row = min(row0 + r, n - 1);
            float4 v = *(const float4*)(X + (size_t)row * 128 + kt * 32 + kq);
            *(float4*)&xs[r][kq] = v;
        }
        for (int e = tid; e < 32 * FOUT / 4; e += NT) {
            *(float4*)&ws[e * 4] = *(const float4*)&W[kt * 32 * FOUT + e * 4];
        }
        __syncthreads();
#pragma unroll 8
        for (int k = 0; k < 32; ++k) {
            float4 bv = *(const float4*)&ws[k * FOUT + ct * 4];
            float a0 = xs[rt * 4 + 0][k];
            float a1 = xs[rt * 4 + 1][k];
            float a2 = xs[rt * 4 + 2][k];
            float a3 = xs[rt * 4 + 3][k];
            acc[0][0] += a0 * bv.x; acc[0][1] += a0 * bv.y; acc[0][2] += a0 * bv.z; acc[0][3] += a0 * bv.w;
            acc[1][0] += a1 * bv.x; acc[1][1] += a1 * bv.y; acc[1][2] += a1 * bv.z; acc[1][3] += a1 * bv.w;
            acc[2][0] += a2 * bv.x; acc[2][1] += a2 * bv.y; acc[2][2] += a2 * bv.z; acc[2][3] += a2 * bv.w;
            acc[3][0] += a3 * bv.x; acc[3][1] += a3 * bv.y; acc[3][2] += a3 * bv.z; acc[3][3] += a3 * bv.w;
        }
        __syncthreads();
    }
    for (int i = 0; i < 4; ++i) {
        int row = row0 + rt * 4 + i;
        if (row < n) {
            float d = dis[row];
            uint2 o;
            o.x = pack_bf16(acc[i][0] * d, acc[i][1] * d);
            o.y = pack_bf16(acc[i][2] * d, acc[i][3] * d);
            *(uint2*)&Yb[(size_t)row * (FOUT / 2) + ct * 2] = o;
        }
    }
}

// ---------------- aggregation (16-wide edge-batched bf16 gathers) ----------------
// out[v] = relu( dis[v] * (hs[v] + sum_{u in nbr(v)} hs[u]) + b )

__global__ __launch_bounds__(256) void k_agg_relu128(
        const uint32* __restrict__ hb, const int* __restrict__ rp,
        const int* __restrict__ col, const float* __restrict__ dis,
        const float* __restrict__ bias, float* __restrict__ out, int n) {
    int wid = threadIdx.x >> 6;
    int lane = threadIdx.x & 63;
    int v = blockIdx.x * 4 + wid;
    if (v >= n) return;
    uint32 mv = hb[(size_t)v * 64 + lane];      // self-loop term (2 bf16)
    float ax = bf_lo(mv), ay = bf_hi(mv);
    int s = __builtin_amdgcn_readfirstlane(rp[v]);
    int e = __builtin_amdgcn_readfirstlane(rp[v + 1]);
    int k = s;
    for (; k + 16 <= e; k += 16) {
        uint32 m[16];
#pragma unroll
        for (int j = 0; j < 16; ++j) {
            int u = col[k + j];
            m[j] = hb[(size_t)u * 64 + lane];
        }
#pragma unroll
        for (int j = 0; j < 16; ++j) { ax += bf_lo(m[j]); ay += bf_hi(m[j]); }
    }
    if (k + 8 <= e) {
        uint32 m[8];
#pragma unroll
        for (int j = 0; j < 8; ++j) m[j] = hb[(size_t)col[k + j] * 64 + lane];
#pragma unroll
        for (int j = 0; j < 8; ++j) { ax += bf_lo(m[j]); ay += bf_hi(m[j]); }
        k += 8;
    }
    if (k + 4 <= e) {
        uint32 m[4];
#pragma unroll
        for (int j = 0; j < 4; ++j) m[j] = hb[(size_t)col[k + j] * 64 + lane];
#pragma unroll
        for (int j = 0; j < 4; ++j) { ax += bf_lo(m[j]); ay += bf_hi(m[j]); }
        k += 4;
    }
    for (; k < e; ++k) {
        uint32 m = hb[(size_t)col[k] * 64 + lane];
        ax += bf_lo(m); ay += bf_hi(m);
    }
    float d = dis[v];
    float2 b = ((const float2*)bias)[lane];
    float ox = fmaxf(d * ax + b.x, 0.f);
    float oy = fmaxf(d * ay + b.y, 0.f);
    ((float2*)out)[(size_t)v * 64 + lane] = make_float2(ox, oy);
}

// final layer: F=64 bf16 rows, fused bias + log_softmax
__global__ __launch_bounds__(256) void k_agg_lsm64(
        const ushort16* __restrict__ hb, const int* __restrict__ rp,
        const int* __restrict__ col, const float* __restrict__ dis,
        const float* __restrict__ bias, float* __restrict__ out, int n) {
    int wid = threadIdx.x >> 6;
    int lane = threadIdx.x & 63;
    int v = blockIdx.x * 4 + wid;
    if (v >= n) return;
    float acc = __uint_as_float((uint32)hb[(size_t)v * 64 + lane] << 16);
    int s = __builtin_amdgcn_readfirstlane(rp[v]);
    int e = __builtin_amdgcn_readfirstlane(rp[v + 1]);
    int k = s;
    for (; k + 16 <= e; k += 16) {
        ushort16 m[16];
#pragma unroll
        for (int j = 0; j < 16; ++j) m[j] = hb[(size_t)col[k + j] * 64 + lane];
#pragma unroll
        for (int j = 0; j < 16; ++j) acc += __uint_as_float((uint32)m[j] << 16);
    }
    if (k + 8 <= e) {
        ushort16 m[8];
#pragma unroll
        for (int j = 0; j < 8; ++j) m[j] = hb[(size_t)col[k + j] * 64 + lane];
#pragma unroll
        for (int j = 0; j < 8; ++j) acc += __uint_as_float((uint32)m[j] << 16);
        k += 8;
    }
    for (; k < e; ++k) acc += __uint_as_float((uint32)hb[(size_t)col[k] * 64 + lane] << 16);
    float val = dis[v] * acc + bias[lane];
    float m = val;
    for (int off = 32; off; off >>= 1) m = fmaxf(m, __shfl_xor(m, off, 64));
    float ex = expf(val - m);
    float ss = ex;
    for (int off = 32; off; off >>= 1) ss += __shfl_xor(ss, off, 64);
    out[(size_t)v * 64 + lane] = val - m - logf(ss);
}

// ---------------- launch ----------------

extern "C" void kernel_launch(void* const* d_in, const int* in_sizes, int n_in,
                              void* d_out, int out_size, void* d_ws, size_t ws_size,
                              hipStream_t stream) {
    const float* x  = (const float*)d_in[0];
    const float* W1 = (const float*)d_in[1];
    const float* b1 = (const float*)d_in[2];
    const float* W2 = (const float*)d_in[3];
    const float* b2 = (const float*)d_in[4];
    const float* W3 = (const float*)d_in[5];
    const float* b3 = (const float*)d_in[6];
    const int*   ei = (const int*)d_in[7];

    const int N = in_sizes[0] / 128;
    const int E = in_sizes[7] / 2;
    const int* srcv = ei;
    const int* dstv = ei + E;

    char* ws = (char*)d_ws;
    size_t off = 0;
    auto alloc = [&](size_t bytes) -> void* {
        void* p = ws + off;
        off += (bytes + 255) & ~(size_t)255;
        return p;
    };
    float*  dis  = (float*)alloc((size_t)N * 4);
    int*    cnt  = (int*)alloc((size_t)N * 4);
    int*    rp   = (int*)alloc((size_t)(N + 1) * 4);
    int*    fill = (int*)alloc((size_t)N * 4);
    int*    col  = (int*)alloc((size_t)E * 4);
    int*    part = (int*)alloc((size_t)1024 * 4);
    uint32* hsb  = (uint32*)alloc((size_t)N * 128 * 2);   // bf16 gather source
    float*  bufF = (float*)alloc((size_t)N * 128 * 4);    // fp32 GEMM input
    float*  outp = (float*)d_out;

    const int tb = 256;
    const int nb = (N + 1023) / 1024;
    k_init_cnt<<<(N + tb - 1) / tb, tb, 0, stream>>>(cnt, N);
    k_count<<<(E + tb - 1) / tb, tb, 0, stream>>>(dstv, cnt, E);
    k_dis<<<(N + tb - 1) / tb, tb, 0, stream>>>(cnt, dis, N);
    k_partial_sums<<<nb, 256, 0, stream>>>(cnt, part, N);
    k_scan_partials<<<1, 1024, 0, stream>>>(part, nb, rp, N, E);
    k_local_scan<<<nb, 256, 0, stream>>>(cnt, part, rp, fill, N);
    k_fill<<<(E + tb - 1) / tb, tb, 0, stream>>>(srcv, dstv, fill, col, E);

    int gblk = (N + 31) / 32;
    int ablk = (N + 3) / 4;
    // layer 1: x -> hsb (bf16) -> bufF (fp32)
    k_gemm_scale<128><<<gblk, 256, 0, stream>>>(x, W1, dis, hsb, N);
    k_agg_relu128<<<ablk, 256, 0, stream>>>(hsb, rp, col, dis, b1, bufF, N);
    // layer 2: bufF -> hsb -> bufF
    k_gemm_scale<128><<<gblk, 256, 0, stream>>>(bufF, W2, dis, hsb, N);
    k_agg_relu128<<<ablk, 256, 0, stream>>>(hsb, rp, col, dis, b2, bufF, N);
    // layer 3: bufF -> hsb (N x 64 bf16) -> d_out
    k_gemm_scale<64><<<gblk, 128, 0, stream>>>(bufF, W3, dis, hsb, N);
    k_agg_lsm64<<<ablk, 256, 0, stream>>>((const ushort16*)hsb, rp, col, dis, b3, outp, N);
}

// Round 5
// 230.063 us; speedup vs baseline: 2.3595x; 1.2088x over previous
//
#include <hip/hip_runtime.h>
#include <hip/hip_bf16.h>
#include <cstdint>

typedef unsigned int uint32;
typedef unsigned short ushort16;

#define EPB 4096   // edges per block in bucket-hist / partition kernels

__device__ inline uint32 pack_bf16(float a, float b) {
    uint32 ua = __float_as_uint(a);
    ua += 0x7fff + ((ua >> 16) & 1);
    uint32 ub = __float_as_uint(b);
    ub += 0x7fff + ((ub >> 16) & 1);
    return (ua >> 16) | (ub & 0xffff0000u);
}
__device__ inline float bf_lo(uint32 w) { return __uint_as_float(w << 16); }
__device__ inline float bf_hi(uint32 w) { return __uint_as_float(w & 0xffff0000u); }

// ---------------- bucket-partition CSR build ----------------
// bucket b = dst >> shift; window = 1<<shift nodes; nb <= 256 buckets.

__global__ void k_init_i32(int* __restrict__ p, int n) {
    int i = blockIdx.x * blockDim.x + threadIdx.x;
    if (i < n) p[i] = 0;
}

__global__ __launch_bounds__(256) void k_bhist(const int* __restrict__ dstv,
                                               int* __restrict__ bhist, int e, int shift) {
    __shared__ int h[256];
    int t = threadIdx.x;
    h[t] = 0;
    __syncthreads();
    int b0 = blockIdx.x * EPB;
#pragma unroll
    for (int i = 0; i < EPB / 256; ++i) {
        int idx = b0 + i * 256 + t;
        if (idx < e) atomicAdd(&h[dstv[idx] >> shift], 1);
    }
    __syncthreads();
    if (h[t]) atomicAdd(&bhist[t], h[t]);
}

__global__ __launch_bounds__(256) void k_bscan(const int* __restrict__ bhist,
                                               int* __restrict__ bpre, int* __restrict__ bcur,
                                               int nb, int e) {
    __shared__ int s[256];
    int t = threadIdx.x;
    int v = (t < nb) ? bhist[t] : 0;
    s[t] = v;
    __syncthreads();
    for (int off = 1; off < 256; off <<= 1) {
        int a = (t >= off) ? s[t - off] : 0;
        __syncthreads();
        s[t] += a;
        __syncthreads();
    }
    if (t < nb) { bpre[t] = s[t] - v; bcur[t] = s[t] - v; }
    if (t == 0) bpre[nb] = e;
}

__global__ __launch_bounds__(256) void k_partition(const int* __restrict__ srcv,
                                                   const int* __restrict__ dstv,
                                                   int* __restrict__ bcur,
                                                   uint2* __restrict__ pairs,
                                                   int e, int shift) {
    __shared__ int h[256], base[256], cur[256];
    int t = threadIdx.x;
    h[t] = 0; cur[t] = 0;
    __syncthreads();
    int s[EPB / 256], d[EPB / 256];
    int b0 = blockIdx.x * EPB;
#pragma unroll
    for (int i = 0; i < EPB / 256; ++i) {
        int idx = b0 + i * 256 + t;
        if (idx < e) {
            s[i] = srcv[idx]; d[i] = dstv[idx];
            atomicAdd(&h[d[i] >> shift], 1);
        } else d[i] = -1;
    }
    __syncthreads();
    if (h[t]) base[t] = atomicAdd(&bcur[t], h[t]);
    __syncthreads();
#pragma unroll
    for (int i = 0; i < EPB / 256; ++i) {
        if (d[i] >= 0) {
            int b = d[i] >> shift;
            int sl = atomicAdd(&cur[b], 1);
            pairs[base[b] + sl] = make_uint2((unsigned)s[i], (unsigned)d[i]);
        }
    }
}

// one block per bucket: dense in-degree counts
__global__ __launch_bounds__(256) void k_bcount(const uint2* __restrict__ pairs,
                                                const int* __restrict__ bpre,
                                                int* __restrict__ cnt, int n, int shift) {
    __shared__ int c[1024];
    int t = threadIdx.x;
    int win = 1 << shift;
    for (int i = t; i < win; i += 256) c[i] = 0;
    __syncthreads();
    int wb = blockIdx.x << shift;
    int e0 = bpre[blockIdx.x], e1 = bpre[blockIdx.x + 1];
    for (int i = e0 + t; i < e1; i += 256) {
        uint2 p = pairs[i];
        atomicAdd(&c[(int)p.y - wb], 1);
    }
    __syncthreads();
    for (int i = t; i < win; i += 256) if (wb + i < n) cnt[wb + i] = c[i];
}

// one block per bucket: CSR fill via LDS cursors, XCD-local col window
__global__ __launch_bounds__(256) void k_bfill(const uint2* __restrict__ pairs,
                                               const int* __restrict__ bpre,
                                               const int* __restrict__ rp,
                                               int* __restrict__ col, int shift) {
    __shared__ int c[1024];
    int t = threadIdx.x;
    int win = 1 << shift;
    for (int i = t; i < win; i += 256) c[i] = 0;
    __syncthreads();
    int wb = blockIdx.x << shift;
    int e0 = bpre[blockIdx.x], e1 = bpre[blockIdx.x + 1];
    for (int i = e0 + t; i < e1; i += 256) {
        uint2 p = pairs[i];
        int sl = atomicAdd(&c[(int)p.y - wb], 1);
        col[rp[p.y] + sl] = (int)p.x;
    }
}

__global__ void k_dis(const int* __restrict__ cnt, float* __restrict__ dis, int n) {
    int i = blockIdx.x * blockDim.x + threadIdx.x;
    if (i < n) dis[i] = rsqrtf((float)(cnt[i] + 1));   // +1 = self-loop
}

// ---------- two-level node scan: cnt -> rp (exclusive) ----------

__global__ __launch_bounds__(256) void k_partial_sums(const int* __restrict__ cnt,
                                                      int* __restrict__ partial, int n) {
    int base = blockIdx.x * 1024 + threadIdx.x * 4;
    int4 v = make_int4(0, 0, 0, 0);
    if (base + 3 < n) v = *(const int4*)(cnt + base);
    else {
        if (base + 0 < n) v.x = cnt[base + 0];
        if (base + 1 < n) v.y = cnt[base + 1];
        if (base + 2 < n) v.z = cnt[base + 2];
    }
    int s = v.x + v.y + v.z + v.w;
    for (int off = 32; off; off >>= 1) s += __shfl_xor(s, off, 64);
    __shared__ int wsum[4];
    int lane = threadIdx.x & 63, wid = threadIdx.x >> 6;
    if (lane == 0) wsum[wid] = s;
    __syncthreads();
    if (threadIdx.x == 0) partial[blockIdx.x] = wsum[0] + wsum[1] + wsum[2] + wsum[3];
}

__global__ __launch_bounds__(1024) void k_scan_partials(int* __restrict__ partial, int nb,
                                                        int* __restrict__ rp, int n, int etot) {
    __shared__ int s[1024];
    int t = threadIdx.x;
    int v = (t < nb) ? partial[t] : 0;
    s[t] = v;
    __syncthreads();
    for (int off = 1; off < 1024; off <<= 1) {
        int add = (t >= off) ? s[t - off] : 0;
        __syncthreads();
        s[t] += add;
        __syncthreads();
    }
    if (t < nb) partial[t] = s[t] - v;
    if (t == 0) rp[n] = etot;
}

__global__ __launch_bounds__(256) void k_local_scan(const int* __restrict__ cnt,
                                                    const int* __restrict__ partial,
                                                    int* __restrict__ rp, int n) {
    int base = blockIdx.x * 1024 + threadIdx.x * 4;
    int4 v = make_int4(0, 0, 0, 0);
    if (base + 3 < n) v = *(const int4*)(cnt + base);
    else {
        if (base + 0 < n) v.x = cnt[base + 0];
        if (base + 1 < n) v.y = cnt[base + 1];
        if (base + 2 < n) v.z = cnt[base + 2];
    }
    int tsum = v.x + v.y + v.z + v.w;
    int lane = threadIdx.x & 63, wid = threadIdx.x >> 6;
    int inc = tsum;
    for (int off = 1; off < 64; off <<= 1) {
        int y = __shfl_up(inc, off, 64);
        if (lane >= off) inc += y;
    }
    int exc = inc - tsum;
    __shared__ int wtot[4];
    if (lane == 63) wtot[wid] = inc;
    __syncthreads();
    int woff = 0;
    for (int w = 0; w < wid; ++w) woff += wtot[w];
    int p0 = partial[blockIdx.x] + woff + exc;
    int p1 = p0 + v.x, p2 = p1 + v.y, p3 = p2 + v.z;
    if (base + 3 < n) {
        *(int4*)&rp[base] = make_int4(p0, p1, p2, p3);
    } else {
        if (base + 0 < n) rp[base + 0] = p0;
        if (base + 1 < n) rp[base + 1] = p1;
        if (base + 2 < n) rp[base + 2] = p2;
    }
}

// ------- GEMM: Yb[r][c] = bf16( dis[r] * sum_k X[r][k] * W[k][c] ) -------

template <int FOUT>
__global__ __launch_bounds__(FOUT * 2) void k_gemm_scale(
        const float* __restrict__ X, const float* __restrict__ W,
        const float* __restrict__ dis, uint32* __restrict__ Yb, int n) {
    constexpr int CT = FOUT / 4;
    constexpr int NT = CT * 8;
    __shared__ float xs[32][132];
    __shared__ float ws[32 * FOUT];
    int tid = threadIdx.x;
    int ct = tid % CT, rt = tid / CT;
    int row0 = blockIdx.x * 32;
    float acc[4][4] = {};

    for (int kt = 0; kt < 4; ++kt) {
        for (int e = tid; e < 256; e += NT) {
            int r = e >> 3, kq = (e & 7) << 2;
            int row = min(row0 + r, n - 1);
            float4 v = *(const float4*)(X + (size_t)row * 128 + kt * 32 + kq);
            *(float4*)&xs[r][kq] = v;
        }
        for (int e = tid; e < 32 * FOUT / 4; e += NT) {
            *(float4*)&ws[e * 4] = *(const float4*)&W[kt * 32 * FOUT + e * 4];
        }
        __syncthreads();
#pragma unroll 8
        for (int k = 0; k < 32; ++k) {
            float4 bv = *(const float4*)&ws[k * FOUT + ct * 4];
            float a0 = xs[rt * 4 + 0][k];
            float a1 = xs[rt * 4 + 1][k];
            float a2 = xs[rt * 4 + 2][k];
            float a3 = xs[rt * 4 + 3][k];
            acc[0][0] += a0 * bv.x; acc[0][1] += a0 * bv.y; acc[0][2] += a0 * bv.z; acc[0][3] += a0 * bv.w;
            acc[1][0] += a1 * bv.x; acc[1][1] += a1 * bv.y; acc[1][2] += a1 * bv.z; acc[1][3] += a1 * bv.w;
            acc[2][0] += a2 * bv.x; acc[2][1] += a2 * bv.y; acc[2][2] += a2 * bv.z; acc[2][3] += a2 * bv.w;
            acc[3][0] += a3 * bv.x; acc[3][1] += a3 * bv.y; acc[3][2] += a3 * bv.z; acc[3][3] += a3 * bv.w;
        }
        __syncthreads();
    }
    for (int i = 0; i < 4; ++i) {
        int row = row0 + rt * 4 + i;
        if (row < n) {
            float d = dis[row];
            uint2 o;
            o.x = pack_bf16(acc[i][0] * d, acc[i][1] * d);
            o.y = pack_bf16(acc[i][2] * d, acc[i][3] * d);
            *(uint2*)&Yb[(size_t)row * (FOUT / 2) + ct * 2] = o;
        }
    }
}

// ---------------- aggregation (16-wide edge-batched bf16 gathers) ----------------

__global__ __launch_bounds__(256) void k_agg_relu128(
        const uint32* __restrict__ hb, const int* __restrict__ rp,
        const int* __restrict__ col, const float* __restrict__ dis,
        const float* __restrict__ bias, float* __restrict__ out, int n) {
    int wid = threadIdx.x >> 6;
    int lane = threadIdx.x & 63;
    int v = blockIdx.x * 4 + wid;
    if (v >= n) return;
    uint32 mv = hb[(size_t)v * 64 + lane];
    float ax = bf_lo(mv), ay = bf_hi(mv);
    int s = __builtin_amdgcn_readfirstlane(rp[v]);
    int e = __builtin_amdgcn_readfirstlane(rp[v + 1]);
    int k = s;
    for (; k + 16 <= e; k += 16) {
        uint32 m[16];
#pragma unroll
        for (int j = 0; j < 16; ++j) {
            int u = col[k + j];
            m[j] = hb[(size_t)u * 64 + lane];
        }
#pragma unroll
        for (int j = 0; j < 16; ++j) { ax += bf_lo(m[j]); ay += bf_hi(m[j]); }
    }
    if (k + 8 <= e) {
        uint32 m[8];
#pragma unroll
        for (int j = 0; j < 8; ++j) m[j] = hb[(size_t)col[k + j] * 64 + lane];
#pragma unroll
        for (int j = 0; j < 8; ++j) { ax += bf_lo(m[j]); ay += bf_hi(m[j]); }
        k += 8;
    }
    if (k + 4 <= e) {
        uint32 m[4];
#pragma unroll
        for (int j = 0; j < 4; ++j) m[j] = hb[(size_t)col[k + j] * 64 + lane];
#pragma unroll
        for (int j = 0; j < 4; ++j) { ax += bf_lo(m[j]); ay += bf_hi(m[j]); }
        k += 4;
    }
    for (; k < e; ++k) {
        uint32 m = hb[(size_t)col[k] * 64 + lane];
        ax += bf_lo(m); ay += bf_hi(m);
    }
    float d = dis[v];
    float2 b = ((const float2*)bias)[lane];
    float ox = fmaxf(d * ax + b.x, 0.f);
    float oy = fmaxf(d * ay + b.y, 0.f);
    ((float2*)out)[(size_t)v * 64 + lane] = make_float2(ox, oy);
}

__global__ __launch_bounds__(256) void k_agg_lsm64(
        const ushort16* __restrict__ hb, const int* __restrict__ rp,
        const int* __restrict__ col, const float* __restrict__ dis,
        const float* __restrict__ bias, float* __restrict__ out, int n) {
    int wid = threadIdx.x >> 6;
    int lane = threadIdx.x & 63;
    int v = blockIdx.x * 4 + wid;
    if (v >= n) return;
    float acc = __uint_as_float((uint32)hb[(size_t)v * 64 + lane] << 16);
    int s = __builtin_amdgcn_readfirstlane(rp[v]);
    int e = __builtin_amdgcn_readfirstlane(rp[v + 1]);
    int k = s;
    for (; k + 16 <= e; k += 16) {
        ushort16 m[16];
#pragma unroll
        for (int j = 0; j < 16; ++j) m[j] = hb[(size_t)col[k + j] * 64 + lane];
#pragma unroll
        for (int j = 0; j < 16; ++j) acc += __uint_as_float((uint32)m[j] << 16);
    }
    if (k + 8 <= e) {
        ushort16 m[8];
#pragma unroll
        for (int j = 0; j < 8; ++j) m[j] = hb[(size_t)col[k + j] * 64 + lane];
#pragma unroll
        for (int j = 0; j < 8; ++j) acc += __uint_as_float((uint32)m[j] << 16);
        k += 8;
    }
    for (; k < e; ++k) acc += __uint_as_float((uint32)hb[(size_t)col[k] * 64 + lane] << 16);
    float val = dis[v] * acc + bias[lane];
    float m = val;
    for (int off = 32; off; off >>= 1) m = fmaxf(m, __shfl_xor(m, off, 64));
    float ex = expf(val - m);
    float ss = ex;
    for (int off = 32; off; off >>= 1) ss += __shfl_xor(ss, off, 64);
    out[(size_t)v * 64 + lane] = val - m - logf(ss);
}

// ---------------- launch ----------------

extern "C" void kernel_launch(void* const* d_in, const int* in_sizes, int n_in,
                              void* d_out, int out_size, void* d_ws, size_t ws_size,
                              hipStream_t stream) {
    const float* x  = (const float*)d_in[0];
    const float* W1 = (const float*)d_in[1];
    const float* b1 = (const float*)d_in[2];
    const float* W2 = (const float*)d_in[3];
    const float* b2 = (const float*)d_in[4];
    const float* W3 = (const float*)d_in[5];
    const float* b3 = (const float*)d_in[6];
    const int*   ei = (const int*)d_in[7];

    const int N = in_sizes[0] / 128;
    const int E = in_sizes[7] / 2;
    const int* srcv = ei;
    const int* dstv = ei + E;

    // bucket shift: windows of 1<<shift nodes, <=256 buckets, window <=1024 (LDS)
    int shift = 8;
    while (((N + (1 << shift) - 1) >> shift) > 256) ++shift;
    const int NB  = (N + (1 << shift) - 1) >> shift;

    char* ws = (char*)d_ws;
    size_t off = 0;
    auto alloc = [&](size_t bytes) -> void* {
        void* p = ws + off;
        off += (bytes + 255) & ~(size_t)255;
        return p;
    };
    float*  dis   = (float*)alloc((size_t)N * 4);
    int*    cnt   = (int*)alloc((size_t)N * 4);
    int*    rp    = (int*)alloc((size_t)(N + 1) * 4);
    int*    col   = (int*)alloc((size_t)E * 4);
    int*    part  = (int*)alloc((size_t)1024 * 4);
    int*    bhist = (int*)alloc((size_t)(NB + 1) * 4);
    int*    bpre  = (int*)alloc((size_t)(NB + 1) * 4);
    int*    bcur  = (int*)alloc((size_t)(NB + 1) * 4);
    uint2*  pairs = (uint2*)alloc((size_t)E * 8);
    uint32* hsb   = (uint32*)alloc((size_t)N * 128 * 2);   // bf16 gather source
    float*  bufF  = (float*)alloc((size_t)N * 128 * 4);    // fp32 GEMM input
    float*  outp  = (float*)d_out;

    const int tb = 256;
    const int nbE = (E + EPB - 1) / EPB;     // blocks over edges
    const int nbS = (N + 1023) / 1024;       // node-scan blocks

    // --- CSR build via bucket partition ---
    k_init_i32<<<(NB + tb - 1) / tb, tb, 0, stream>>>(bhist, NB);
    k_bhist<<<nbE, 256, 0, stream>>>(dstv, bhist, E, shift);
    k_bscan<<<1, 256, 0, stream>>>(bhist, bpre, bcur, NB, E);
    k_partition<<<nbE, 256, 0, stream>>>(srcv, dstv, bcur, pairs, E, shift);
    k_bcount<<<NB, 256, 0, stream>>>(pairs, bpre, cnt, N, shift);
    k_dis<<<(N + tb - 1) / tb, tb, 0, stream>>>(cnt, dis, N);
    k_partial_sums<<<nbS, 256, 0, stream>>>(cnt, part, N);
    k_scan_partials<<<1, 1024, 0, stream>>>(part, nbS, rp, N, E);
    k_local_scan<<<nbS, 256, 0, stream>>>(cnt, part, rp, N);
    k_bfill<<<NB, 256, 0, stream>>>(pairs, bpre, rp, col, shift);

    // --- 3 GCN layers ---
    int gblk = (N + 31) / 32;
    int ablk = (N + 3) / 4;
    k_gemm_scale<128><<<gblk, 256, 0, stream>>>(x, W1, dis, hsb, N);
    k_agg_relu128<<<ablk, 256, 0, stream>>>(hsb, rp, col, dis, b1, bufF, N);
    k_gemm_scale<128><<<gblk, 256, 0, stream>>>(bufF, W2, dis, hsb, N);
    k_agg_relu128<<<ablk, 256, 0, stream>>>(hsb, rp, col, dis, b2, bufF, N);
    k_gemm_scale<64><<<gblk, 128, 0, stream>>>(bufF, W3, dis, hsb, N);
    k_agg_lsm64<<<ablk, 256, 0, stream>>>((const ushort16*)hsb, rp, col, dis, b3, outp, N);
}

// Round 6
// 207.703 us; speedup vs baseline: 2.6136x; 1.1077x over previous
//
#include <hip/hip_runtime.h>
#include <hip/hip_bf16.h>
#include <cstdint>

typedef unsigned int uint32;
typedef __attribute__((ext_vector_type(8))) short short8;   // 8 bf16 (4 VGPRs)
typedef __attribute__((ext_vector_type(4))) float f32x4;    // MFMA C/D

#define EPB 4096   // edges per block in bucket-hist / partition kernels

__device__ inline unsigned short bf16r(float f) {
    uint32 u = __float_as_uint(f);
    u += 0x7fff + ((u >> 16) & 1);
    return (unsigned short)(u >> 16);
}
__device__ inline uint32 pack_bf16(float a, float b) {
    return (uint32)bf16r(a) | ((uint32)bf16r(b) << 16);
}
__device__ inline float bf_lo(uint32 w) { return __uint_as_float(w << 16); }
__device__ inline float bf_hi(uint32 w) { return __uint_as_float(w & 0xffff0000u); }

// ---------------- bucket-partition CSR build ----------------
// bucket b = dst >> 8 ; window = 256 nodes ; NB = ceil(N/256) buckets (<=256)

__global__ void k_init_i32(int* __restrict__ p, int n) {
    int i = blockIdx.x * blockDim.x + threadIdx.x;
    if (i < n) p[i] = 0;
}

__global__ __launch_bounds__(256) void k_bhist(const int* __restrict__ dstv,
                                               int* __restrict__ bhist, int e) {
    __shared__ int h[256];
    int t = threadIdx.x;
    h[t] = 0;
    __syncthreads();
    int b0 = blockIdx.x * EPB;
#pragma unroll
    for (int i = 0; i < EPB / 256; ++i) {
        int idx = b0 + i * 256 + t;
        if (idx < e) atomicAdd(&h[dstv[idx] >> 8], 1);
    }
    __syncthreads();
    if (h[t]) atomicAdd(&bhist[t], h[t]);
}

__global__ __launch_bounds__(256) void k_bscan(const int* __restrict__ bhist,
                                               int* __restrict__ bpre, int* __restrict__ bcur,
                                               int nb, int e, int* __restrict__ rp, int n) {
    __shared__ int s[256];
    int t = threadIdx.x;
    int v = (t < nb) ? bhist[t] : 0;
    s[t] = v;
    __syncthreads();
    for (int off = 1; off < 256; off <<= 1) {
        int a = (t >= off) ? s[t - off] : 0;
        __syncthreads();
        s[t] += a;
        __syncthreads();
    }
    if (t < nb) { bpre[t] = s[t] - v; bcur[t] = s[t] - v; }
    if (t == 0) { bpre[nb] = e; rp[n] = e; }
}

__global__ __launch_bounds__(256) void k_partition(const int* __restrict__ srcv,
                                                   const int* __restrict__ dstv,
                                                   int* __restrict__ bcur,
                                                   uint2* __restrict__ pairs, int e) {
    __shared__ int h[256], base[256], cur[256];
    int t = threadIdx.x;
    h[t] = 0; cur[t] = 0;
    __syncthreads();
    int s[EPB / 256], d[EPB / 256];
    int b0 = blockIdx.x * EPB;
#pragma unroll
    for (int i = 0; i < EPB / 256; ++i) {
        int idx = b0 + i * 256 + t;
        if (idx < e) {
            s[i] = srcv[idx]; d[i] = dstv[idx];
            atomicAdd(&h[d[i] >> 8], 1);
        } else d[i] = -1;
    }
    __syncthreads();
    if (h[t]) base[t] = atomicAdd(&bcur[t], h[t]);
    __syncthreads();
#pragma unroll
    for (int i = 0; i < EPB / 256; ++i) {
        if (d[i] >= 0) {
            int b = d[i] >> 8;
            int sl = atomicAdd(&cur[b], 1);
            pairs[base[b] + sl] = make_uint2((unsigned)s[i], (unsigned)d[i]);
        }
    }
}

// one block per bucket: LDS degree count -> LDS scan -> rp, dis, col
__global__ __launch_bounds__(256) void k_bfinish(const uint2* __restrict__ pairs,
                                                 const int* __restrict__ bpre,
                                                 int* __restrict__ rp, float* __restrict__ dis,
                                                 int* __restrict__ col, int n) {
    __shared__ int c[256], sc[256], cur[256];
    int t = threadIdx.x;
    c[t] = 0; cur[t] = 0;
    __syncthreads();
    int wb = blockIdx.x << 8;
    int e0 = bpre[blockIdx.x], e1 = bpre[blockIdx.x + 1];
    for (int i = e0 + t; i < e1; i += 256) atomicAdd(&c[(int)pairs[i].y - wb], 1);
    __syncthreads();
    int own = c[t];
    sc[t] = own;
    __syncthreads();
    for (int off = 1; off < 256; off <<= 1) {
        int a = (t >= off) ? sc[t - off] : 0;
        __syncthreads();
        sc[t] += a;
        __syncthreads();
    }
    int base = bpre[blockIdx.x] + sc[t] - own;
    __syncthreads();
    sc[t] = base;
    int v = wb + t;
    if (v < n) { rp[v] = base; dis[v] = rsqrtf((float)(own + 1)); }
    __syncthreads();
    for (int i = e0 + t; i < e1; i += 256) {
        uint2 p = pairs[i];
        int bl = (int)p.y - wb;
        int sl = atomicAdd(&cur[bl], 1);
        col[sc[bl] + sl] = (int)p.x;
    }
}

// ---------------- W -> W^T bf16 (one block per matrix) ----------------

__global__ __launch_bounds__(256) void k_wprep(const float* __restrict__ W1,
                                               const float* __restrict__ W2,
                                               const float* __restrict__ W3,
                                               unsigned short* __restrict__ Wt1,
                                               unsigned short* __restrict__ Wt2,
                                               unsigned short* __restrict__ Wt3) {
    const float* W = blockIdx.x == 0 ? W1 : (blockIdx.x == 1 ? W2 : W3);
    unsigned short* Wt = blockIdx.x == 0 ? Wt1 : (blockIdx.x == 1 ? Wt2 : Wt3);
    int F = blockIdx.x == 2 ? 64 : 128;
    for (int i = threadIdx.x; i < 128 * F; i += 256) {
        int k = i / F, c = i % F;
        Wt[c * 128 + k] = bf16r(W[i]);
    }
}

// ------- MFMA GEMM: Yb[r][c] = bf16( dis[r] * sum_k X[r][k] * W[k][c] ) -------
// K=128. 256 thr = 4 waves, 16 rows/wave, 64 rows/block. Wt = W^T bf16 [FOUT][128].
// 16x16x32 bf16 MFMA: A lane: row=lane&15, k=(lane>>4)*8+j ; B lane: col=lane&15, same k.
// C/D: col=lane&15, row=(lane>>4)*4+reg  [m89-verified]

template <int FOUT, bool BF16IN>
__global__ __launch_bounds__(256) void k_gemm_mfma(
        const void* __restrict__ Xv, const unsigned short* __restrict__ Wt,
        const float* __restrict__ dis, unsigned short* __restrict__ Yb, int n) {
    constexpr int CT = FOUT / 16;
    int lane = threadIdx.x & 63;
    int wv = threadIdx.x >> 6;
    int r16 = lane & 15, kg = lane >> 4;
    int rowA = blockIdx.x * 64 + wv * 16 + r16;
    int ra = min(rowA, n - 1);
    short8 afr[4];
    if (BF16IN) {
        const unsigned short* Xb = (const unsigned short*)Xv;
#pragma unroll
        for (int ks = 0; ks < 4; ++ks)
            afr[ks] = *(const short8*)(Xb + (size_t)ra * 128 + ks * 32 + kg * 8);
    } else {
        const float* Xf = (const float*)Xv;
#pragma unroll
        for (int ks = 0; ks < 4; ++ks) {
            const float* p = Xf + (size_t)ra * 128 + ks * 32 + kg * 8;
            float4 f0 = *(const float4*)p;
            float4 f1 = *(const float4*)(p + 4);
            short8 a;
            a[0] = (short)bf16r(f0.x); a[1] = (short)bf16r(f0.y);
            a[2] = (short)bf16r(f0.z); a[3] = (short)bf16r(f0.w);
            a[4] = (short)bf16r(f1.x); a[5] = (short)bf16r(f1.y);
            a[6] = (short)bf16r(f1.z); a[7] = (short)bf16r(f1.w);
            afr[ks] = a;
        }
    }
    f32x4 acc[CT];
#pragma unroll
    for (int c = 0; c < CT; ++c) acc[c] = (f32x4){0.f, 0.f, 0.f, 0.f};
#pragma unroll
    for (int ks = 0; ks < 4; ++ks) {
#pragma unroll
        for (int c = 0; c < CT; ++c) {
            short8 b = *(const short8*)(Wt + (c * 16 + r16) * 128 + ks * 32 + kg * 8);
            acc[c] = __builtin_amdgcn_mfma_f32_16x16x32_bf16(afr[ks], b, acc[c], 0, 0, 0);
        }
    }
    int rbase = blockIdx.x * 64 + wv * 16 + kg * 4;
#pragma unroll
    for (int j = 0; j < 4; ++j) {
        int row = rbase + j;
        if (row < n) {
            float d = dis[row];
#pragma unroll
            for (int c = 0; c < CT; ++c)
                Yb[(size_t)row * FOUT + c * 16 + r16] = bf16r(acc[c][j] * d);
        }
    }
}

// ---------------- aggregation (16-wide edge-batched bf16 gathers) ----------------
// outb[v] = bf16( relu( dis[v] * (hs[v] + sum_nbr hs[u]) + b ) )

__global__ __launch_bounds__(256) void k_agg_relu128(
        const uint32* __restrict__ hb, const int* __restrict__ rp,
        const int* __restrict__ col, const float* __restrict__ dis,
        const float* __restrict__ bias, uint32* __restrict__ outb, int n) {
    int wid = threadIdx.x >> 6;
    int lane = threadIdx.x & 63;
    int v = blockIdx.x * 4 + wid;
    if (v >= n) return;
    uint32 mv = hb[(size_t)v * 64 + lane];
    float ax = bf_lo(mv), ay = bf_hi(mv);
    int s = __builtin_amdgcn_readfirstlane(rp[v]);
    int e = __builtin_amdgcn_readfirstlane(rp[v + 1]);
    int k = s;
    for (; k + 16 <= e; k += 16) {
        uint32 m[16];
#pragma unroll
        for (int j = 0; j < 16; ++j) {
            int u = col[k + j];
            m[j] = hb[(size_t)u * 64 + lane];
        }
#pragma unroll
        for (int j = 0; j < 16; ++j) { ax += bf_lo(m[j]); ay += bf_hi(m[j]); }
    }
    if (k + 8 <= e) {
        uint32 m[8];
#pragma unroll
        for (int j = 0; j < 8; ++j) m[j] = hb[(size_t)col[k + j] * 64 + lane];
#pragma unroll
        for (int j = 0; j < 8; ++j) { ax += bf_lo(m[j]); ay += bf_hi(m[j]); }
        k += 8;
    }
    if (k + 4 <= e) {
        uint32 m[4];
#pragma unroll
        for (int j = 0; j < 4; ++j) m[j] = hb[(size_t)col[k + j] * 64 + lane];
#pragma unroll
        for (int j = 0; j < 4; ++j) { ax += bf_lo(m[j]); ay += bf_hi(m[j]); }
        k += 4;
    }
    for (; k < e; ++k) {
        uint32 m = hb[(size_t)col[k] * 64 + lane];
        ax += bf_lo(m); ay += bf_hi(m);
    }
    float d = dis[v];
    float2 b = ((const float2*)bias)[lane];
    float ox = fmaxf(d * ax + b.x, 0.f);
    float oy = fmaxf(d * ay + b.y, 0.f);
    outb[(size_t)v * 64 + lane] = pack_bf16(ox, oy);
}

// final layer: F=64 bf16 rows, fused bias + log_softmax (fp32 out)
__global__ __launch_bounds__(256) void k_agg_lsm64(
        const unsigned short* __restrict__ hb, const int* __restrict__ rp,
        const int* __restrict__ col, const float* __restrict__ dis,
        const float* __restrict__ bias, float* __restrict__ out, int n) {
    int wid = threadIdx.x >> 6;
    int lane = threadIdx.x & 63;
    int v = blockIdx.x * 4 + wid;
    if (v >= n) return;
    float acc = __uint_as_float((uint32)hb[(size_t)v * 64 + lane] << 16);
    int s = __builtin_amdgcn_readfirstlane(rp[v]);
    int e = __builtin_amdgcn_readfirstlane(rp[v + 1]);
    int k = s;
    for (; k + 16 <= e; k += 16) {
        unsigned short m[16];
#pragma unroll
        for (int j = 0; j < 16; ++j) m[j] = hb[(size_t)col[k + j] * 64 + lane];
#pragma unroll
        for (int j = 0; j < 16; ++j) acc += __uint_as_float((uint32)m[j] << 16);
    }
    if (k + 8 <= e) {
        unsigned short m[8];
#pragma unroll
        for (int j = 0; j < 8; ++j) m[j] = hb[(size_t)col[k + j] * 64 + lane];
#pragma unroll
        for (int j = 0; j < 8; ++j) acc += __uint_as_float((uint32)m[j] << 16);
        k += 8;
    }
    for (; k < e; ++k) acc += __uint_as_float((uint32)hb[(size_t)col[k] * 64 + lane] << 16);
    float val = dis[v] * acc + bias[lane];
    float m = val;
    for (int off = 32; off; off >>= 1) m = fmaxf(m, __shfl_xor(m, off, 64));
    float ex = expf(val - m);
    float ss = ex;
    for (int off = 32; off; off >>= 1) ss += __shfl_xor(ss, off, 64);
    out[(size_t)v * 64 + lane] = val - m - logf(ss);
}

// ---------------- launch ----------------

extern "C" void kernel_launch(void* const* d_in, const int* in_sizes, int n_in,
                              void* d_out, int out_size, void* d_ws, size_t ws_size,
                              hipStream_t stream) {
    const float* x  = (const float*)d_in[0];
    const float* W1 = (const float*)d_in[1];
    const float* b1 = (const float*)d_in[2];
    const float* W2 = (const float*)d_in[3];
    const float* b2 = (const float*)d_in[4];
    const float* W3 = (const float*)d_in[5];
    const float* b3 = (const float*)d_in[6];
    const int*   ei = (const int*)d_in[7];

    const int N = in_sizes[0] / 128;
    const int E = in_sizes[7] / 2;
    const int* srcv = ei;
    const int* dstv = ei + E;
    const int NB = (N + 255) >> 8;   // 256-node buckets (<=256 buckets for N<=65536)

    char* ws = (char*)d_ws;
    size_t off = 0;
    auto alloc = [&](size_t bytes) -> void* {
        void* p = ws + off;
        off += (bytes + 255) & ~(size_t)255;
        return p;
    };
    float*          dis   = (float*)alloc((size_t)N * 4);
    int*            rp    = (int*)alloc((size_t)(N + 1) * 4);
    int*            col   = (int*)alloc((size_t)E * 4);
    int*            bhist = (int*)alloc((size_t)(NB + 1) * 4);
    int*            bpre  = (int*)alloc((size_t)(NB + 1) * 4);
    int*            bcur  = (int*)alloc((size_t)(NB + 1) * 4);
    uint2*          pairs = (uint2*)alloc((size_t)E * 8);
    unsigned short* Wt1   = (unsigned short*)alloc(128 * 128 * 2);
    unsigned short* Wt2   = (unsigned short*)alloc(128 * 128 * 2);
    unsigned short* Wt3   = (unsigned short*)alloc(64 * 128 * 2);
    unsigned short* hsb   = (unsigned short*)alloc((size_t)N * 128 * 2);  // GEMM out / gather src
    unsigned short* hbX   = (unsigned short*)alloc((size_t)N * 128 * 2);  // agg out / GEMM in
    float*          outp  = (float*)d_out;

    const int tb = 256;
    const int nbE = (E + EPB - 1) / EPB;

    // --- CSR build ---
    k_init_i32<<<(NB + tb - 1) / tb, tb, 0, stream>>>(bhist, NB);
    k_bhist<<<nbE, 256, 0, stream>>>(dstv, bhist, E);
    k_bscan<<<1, 256, 0, stream>>>(bhist, bpre, bcur, NB, E, rp, N);
    k_partition<<<nbE, 256, 0, stream>>>(srcv, dstv, bcur, pairs, E);
    k_bfinish<<<NB, 256, 0, stream>>>(pairs, bpre, rp, dis, col, N);
    k_wprep<<<3, 256, 0, stream>>>(W1, W2, W3, Wt1, Wt2, Wt3);

    // --- 3 GCN layers ---
    int gblk = (N + 63) / 64;
    int ablk = (N + 3) / 4;
    k_gemm_mfma<128, false><<<gblk, 256, 0, stream>>>(x, Wt1, dis, hsb, N);
    k_agg_relu128<<<ablk, 256, 0, stream>>>((const uint32*)hsb, rp, col, dis, b1, (uint32*)hbX, N);
    k_gemm_mfma<128, true><<<gblk, 256, 0, stream>>>(hbX, Wt2, dis, hsb, N);
    k_agg_relu128<<<ablk, 256, 0, stream>>>((const uint32*)hsb, rp, col, dis, b2, (uint32*)hbX, N);
    k_gemm_mfma<64, true><<<gblk, 256, 0, stream>>>(hbX, Wt3, dis, hsb, N);
    k_agg_lsm64<<<ablk, 256, 0, stream>>>(hsb, rp, col, dis, b3, outp, N);
}